// Round 4
// baseline (283.362 us; speedup 1.0000x reference)
//
#include <hip/hip_runtime.h>

// GCN_84499186582104 — fully fused, TWO batches per thread (8 lanes/batch).
// B=131072, V=8, NFEAT=32, NHID1=16, NHID12=8, NCLASS=2.
// R11 (base = R10, 90us kernel / 273us JSON):
//   Post-mortem R10: occupancy 36->47% but duration flat; VALU 30%, LDS
//   ~30%, HBM 16% -> latency-bound serial chain per wave, not
//   occupancy-starved. s_load weights share lgkmcnt with ds_read ->
//   per-FMA waits serialize both pipes; R10's natural-layout doubled
//   scalar-load count.
//   Changes:
//   - 2 independent batches per thread (slot, slot+32), phases
//     interleaved: two dependency chains fill each other's stall slots
//     (~2x ILP at same occupancy); wave count halves.
//   - KSTEP2 loads each weight pair ONCE and feeds both batches' FMAs:
//     scalar-load (lgkmcnt) traffic per batch halved.
//   - wf/bf prefetched at top; type written to LDS at load time.
//   - VGPR budget: __launch_bounds__(256,4) = 128 cap; expect ~96-112.
//     Spill tripwire = WRITE_SIZE >> 1MB (R8 lesson).
//   LDS = 4 waves x 16 cells x 140 floats = 35840 B -> 4 blocks/CU
//   (16 waves, 50% cap; >= R10's observed ~15 waves, each with 2x work).

#define SLOTS 64      // batches per block (2 per thread)
#define NTHREADS 256  // 8 threads per batch-lane-group

typedef float v2f __attribute__((ext_vector_type(2)));
typedef float4 __attribute__((aligned(4))) f4u;   // dword-aligned float4 load

__device__ __forceinline__ float grp_sum8(float x) {
    x += __shfl_xor(x, 1);
    x += __shfl_xor(x, 2);
    x += __shfl_xor(x, 4);
    return x;
}
__device__ __forceinline__ void wavefence() { __builtin_amdgcn_wave_barrier(); }
__device__ __forceinline__ v2f mkv(float a, float b) { v2f r; r.x = a; r.y = b; return r; }
__device__ __forceinline__ v2f vfma(v2f a, v2f b, v2f c) { return __builtin_elementwise_fma(a, b, c); }

// LDS float layout: per-wave region of 2240 floats = 16 cells x 140.
//   cell(g) base: (tid>>6)*2240 + (g*8 + sl)*140,  sl = slot&7, g = 0,1
//   within a cell (per batch):
//     xstage:  n*16 + ((c + (n>>1) + sl)&3)*4      [0,128)
//     A(Fk/S): 64 + o*8 + w                        [64,128) (stage-dead alias)
//     g-rows:  r*8                                 [0,64)
//     pool:    vp*16 + o*2 (Y), +1 (h2)            [0,128)
//     type:    128 + vp                            [128,136) (never aliased)
//   Slot stride 140 (=12 mod 32 banks): verified <=2-way / minimal patterns.

// One K-step for BOTH batches: weight pairs loaded once, used twice.
#define KSTEP2(kk, cb) { \
    const int cell = (((kk) + (v >> 1) + sl) & 3) << 2; \
    const float4 qA = *(const float4*)(SB0 + v * 16 + cell); \
    const float4 qB = *(const float4*)(SB1 + v * 16 + cell); \
    const v2f fA01 = mkv(qA.x, qA.y), fA23 = mkv(qA.z, qA.w); \
    const v2f fB01 = mkv(qB.x, qB.y), fB23 = mkv(qB.z, qB.w); \
    _Pragma("unroll") \
    for (int o = 0; o < 8; ++o) { \
        const v2f w01 = *(const v2f*)(wb + o * 32 + (cb)); \
        const v2f w23 = *(const v2f*)(wb + o * 32 + (cb) + 2); \
        Fko[0][o] = vfma(fA01, w01, Fko[0][o]); \
        Fko[0][o] = vfma(fA23, w23, Fko[0][o]); \
        Fko[1][o] = vfma(fB01, w01, Fko[1][o]); \
        Fko[1][o] = vfma(fB23, w23, Fko[1][o]); \
    } \
    const float fuA[4] = { qA.x, qA.y, qA.z, qA.w }; \
    const float fuB[4] = { qB.x, qB.y, qB.z, qB.w }; \
    _Pragma("unroll") \
    for (int u = 0; u < 4; ++u) { \
        const int c = (cb) + u; \
        const v2f fa = mkv(fuA[u], fuA[u]); \
        const v2f fb = mkv(fuB[u], fuB[u]); \
        _Pragma("unroll") \
        for (int p = 0; p < 8; ++p) { \
            const v2f wp = *(const v2f*)(w1 + c * 16 + 2 * p); \
            g12[0][p] = vfma(fa, wp, g12[0][p]); \
            g12[1][p] = vfma(fb, wp, g12[1][p]); \
        } \
    } }

__global__ __launch_bounds__(NTHREADS, 4)
void gcn_fused(const float* __restrict__ x,
               const float* __restrict__ adj,
               const float* __restrict__ edge,
               const float* __restrict__ wb, const float* __restrict__ bb,
               const float* __restrict__ w1, const float* __restrict__ b1,
               const float* __restrict__ w2, const float* __restrict__ b2,
               const float* __restrict__ wg,
               const float* __restrict__ wf, const float* __restrict__ bf,
               float* __restrict__ out, int nGroups)
{
    __shared__ __align__(16) float lds[8960];   // 35840 B

    const int tid  = threadIdx.x;
    const int slot = tid >> 3;      // 0..31
    const int v    = tid & 7;
    const int sl   = slot & 7;
    float* SB0 = &lds[(tid >> 6) * 2240 + sl * 140];
    float* SB1 = SB0 + 1120;        // cells 8..15 of the wave region
    float* SBg[2] = { SB0, SB1 };

    long long base = (long long)blockIdx.x * SLOTS + slot;
    const long long bmax = (long long)nGroups * SLOTS - 1;
    size_t b[2];
#pragma unroll
    for (int g = 0; g < 2; ++g) {
        long long t = base + g * 32;
        if (t > bmax) t = bmax;
        b[g] = (size_t)t;
    }

    // ---- classifier weights prefetched (lane-indexed; tiny) ----
    const float wfv0 = wf[v], wfv1 = wf[8 + v];

    // ---- phase-A x loads for both batches ----
    const float* xb[2] = { x + b[0] * 264, x + b[1] * 264 };
    const int nb = v & 4;           // this lane covers nodes nb..nb+3
    const int cl = v & 3;           // ... feature chunk cl of each
    float4 xa[2][4];
#pragma unroll
    for (int g = 0; g < 2; ++g)
#pragma unroll
        for (int i = 0; i < 4; ++i)
            xa[g][i] = *(const f4u*)(xb[g] + (nb + i) * 33 + 1 + cl * 4);

    // type written to its (never-aliased) LDS home immediately
#pragma unroll
    for (int g = 0; g < 2; ++g) SBg[g][128 + v] = xb[g][v * 33];

    // ---- stage phase A, issue phase-B loads ----
#pragma unroll
    for (int g = 0; g < 2; ++g)
#pragma unroll
        for (int i = 0; i < 4; ++i) {
            const int n = nb + i;
            *(float4*)(SBg[g] + n * 16 + (((cl + (n >> 1) + sl) & 3) << 2)) = xa[g][i];
        }
    float4 xc[2][4];
#pragma unroll
    for (int g = 0; g < 2; ++g)
#pragma unroll
        for (int i = 0; i < 4; ++i)
            xc[g][i] = *(const f4u*)(xb[g] + (nb + i) * 33 + 17 + cl * 4);
    wavefence();

    // ---- Fk + g1 over features 0..15 ----
    v2f Fko[2][8];
    v2f g12[2][8];
#pragma unroll
    for (int g = 0; g < 2; ++g)
#pragma unroll
        for (int p = 0; p < 8; ++p) { Fko[g][p] = mkv(0.f, 0.f); g12[g][p] = mkv(0.f, 0.f); }

    KSTEP2(0, 0) KSTEP2(1, 4) KSTEP2(2, 8) KSTEP2(3, 12)
    wavefence();                    // phase-A reads done -> restage same cells
#pragma unroll
    for (int g = 0; g < 2; ++g)
#pragma unroll
        for (int i = 0; i < 4; ++i) {
            const int n = nb + i;
            *(float4*)(SBg[g] + n * 16 + (((cl + (n >> 1) + sl) & 3) << 2)) = xc[g][i];
        }
    wavefence();

    // adj/edge issued here: 2nd KSTEP block (~400 VALU) covers the latency,
    // and they are out of the register picture during the 1st block.
    float4 a0[2], a1[2], e0[2], e1[2];
#pragma unroll
    for (int g = 0; g < 2; ++g) {
        const float4* ar = (const float4*)(adj  + b[g] * 64 + (size_t)v * 8);
        const float4* er = (const float4*)(edge + b[g] * 64 + (size_t)v * 8);
        a0[g] = ar[0]; a1[g] = ar[1];
        e0[g] = er[0]; e1[g] = er[1];
    }

    KSTEP2(0, 16) KSTEP2(1, 20) KSTEP2(2, 24) KSTEP2(3, 28)
    wavefence();                    // stage dead -> A / g-rows may overwrite

    // ---- finalize Fk column: hadd + bias; publish Fk column + g1 half 0 ----
    float Fks[2][8];
#pragma unroll
    for (int g = 0; g < 2; ++g)
#pragma unroll
        for (int o = 0; o < 8; ++o) Fks[g][o] = Fko[g][o].x + Fko[g][o].y + bb[o];

#pragma unroll
    for (int g = 0; g < 2; ++g) {
        float* A = SBg[g] + 64;
#pragma unroll
        for (int o = 0; o < 8; ++o) A[o * 8 + v] = Fks[g][o];
        float4* gp = (float4*)(SBg[g] + v * 8);
        gp[0] = make_float4(g12[g][0].x, g12[g][0].y, g12[g][1].x, g12[g][1].y);
        gp[1] = make_float4(g12[g][2].x, g12[g][2].y, g12[g][3].x, g12[g][3].y);
    }
    wavefence();

    // own column as pairs over m
    v2f Fk2[2][4];
#pragma unroll
    for (int g = 0; g < 2; ++g)
#pragma unroll
        for (int p = 0; p < 4; ++p) Fk2[g][p] = mkv(Fks[g][2 * p], Fks[g][2 * p + 1]);

    // ---- M[o][v] = dot(Fk row o, Fk column v) ----
    float M[2][8];
#pragma unroll
    for (int g = 0; g < 2; ++g) {
        const float* A = SBg[g] + 64;
#pragma unroll
        for (int o = 0; o < 8; ++o) {
            const float4* fr = (const float4*)(A + o * 8);
            const float4 r0 = fr[0], r1 = fr[1];
            v2f acc = mkv(0.f, 0.f);
            acc = vfma(mkv(r0.x, r0.y), Fk2[g][0], acc);
            acc = vfma(mkv(r0.z, r0.w), Fk2[g][1], acc);
            acc = vfma(mkv(r1.x, r1.y), Fk2[g][2], acc);
            acc = vfma(mkv(r1.z, r1.w), Fk2[g][3], acc);
            M[g][o] = acc.x + acc.y;
        }
    }
    wavefence();

    // ---- softmax over o; store S column ----
#pragma unroll
    for (int g = 0; g < 2; ++g) {
        float mx = M[g][0];
#pragma unroll
        for (int o = 1; o < 8; ++o) mx = fmaxf(mx, M[g][o]);
        float ssum = 0.f;
#pragma unroll
        for (int o = 0; o < 8; ++o) { M[g][o] = __expf(M[g][o] - mx); ssum += M[g][o]; }
        const float sinv = 1.f / ssum;
        float* A = SBg[g] + 64;
#pragma unroll
        for (int o = 0; o < 8; ++o) A[o * 8 + v] = M[g][o] * sinv;
    }
    wavefence();

    // ---- W row: W = adj * (S + edge) ----
    v2f W2[2][4];
#pragma unroll
    for (int g = 0; g < 2; ++g) {
        const float4* sr = (const float4*)(SBg[g] + 64 + v * 8);
        const float4 s0 = sr[0], s1 = sr[1];
        W2[g][0] = mkv(a0[g].x, a0[g].y) * (mkv(s0.x, s0.y) + mkv(e0[g].x, e0[g].y));
        W2[g][1] = mkv(a0[g].z, a0[g].w) * (mkv(s0.z, s0.w) + mkv(e0[g].z, e0[g].w));
        W2[g][2] = mkv(a1[g].x, a1[g].y) * (mkv(s1.x, s1.y) + mkv(e1[g].x, e1[g].y));
        W2[g][3] = mkv(a1[g].z, a1[g].w) * (mkv(s1.z, s1.w) + mkv(e1[g].z, e1[g].w));
    }

    // ---- layer 1: h = leaky(W @ g1 + b1), g1 consumed in two halves ----
    v2f m1[2][8];
#pragma unroll
    for (int g = 0; g < 2; ++g)
#pragma unroll
        for (int p = 0; p < 8; ++p) m1[g][p] = mkv(0.f, 0.f);
#pragma unroll
    for (int g = 0; g < 2; ++g)
#pragma unroll
        for (int w = 0; w < 8; ++w) {             // half 0: g1[:,0:8]
            const float wv = (w & 1) ? W2[g][w >> 1].y : W2[g][w >> 1].x;
            const v2f f2 = mkv(wv, wv);
            const float4* gp = (const float4*)(SBg[g] + w * 8);
            const float4 q0 = gp[0], q1 = gp[1];
            m1[g][0] = vfma(f2, mkv(q0.x, q0.y), m1[g][0]);
            m1[g][1] = vfma(f2, mkv(q0.z, q0.w), m1[g][1]);
            m1[g][2] = vfma(f2, mkv(q1.x, q1.y), m1[g][2]);
            m1[g][3] = vfma(f2, mkv(q1.z, q1.w), m1[g][3]);
        }
    wavefence();                                  // half-0 reads done
#pragma unroll
    for (int g = 0; g < 2; ++g) {                 // publish half 1: g1[:,8:16]
        float4* gp = (float4*)(SBg[g] + v * 8);
        gp[0] = make_float4(g12[g][4].x, g12[g][4].y, g12[g][5].x, g12[g][5].y);
        gp[1] = make_float4(g12[g][6].x, g12[g][6].y, g12[g][7].x, g12[g][7].y);
    }
    wavefence();
#pragma unroll
    for (int g = 0; g < 2; ++g)
#pragma unroll
        for (int w = 0; w < 8; ++w) {             // half 1
            const float wv = (w & 1) ? W2[g][w >> 1].y : W2[g][w >> 1].x;
            const v2f f2 = mkv(wv, wv);
            const float4* gp = (const float4*)(SBg[g] + w * 8);
            const float4 q0 = gp[0], q1 = gp[1];
            m1[g][4] = vfma(f2, mkv(q0.x, q0.y), m1[g][4]);
            m1[g][5] = vfma(f2, mkv(q0.z, q0.w), m1[g][5]);
            m1[g][6] = vfma(f2, mkv(q1.x, q1.y), m1[g][6]);
            m1[g][7] = vfma(f2, mkv(q1.z, q1.w), m1[g][7]);
        }
    v2f h[2][8];
    {
        const v2f k01 = mkv(0.01f, 0.01f);
#pragma unroll
        for (int g = 0; g < 2; ++g)
#pragma unroll
            for (int p = 0; p < 8; ++p) {
                const v2f t = m1[g][p] + *(const v2f*)(b1 + 2 * p);
                h[g][p] = __builtin_elementwise_max(t, t * k01);   // leaky
            }
    }

    // ---- g2 row: g2[n] = dot(h, w2[:,n]) (w2 pairs loaded once, used 2x) ----
    v2f g22[2][4];
#pragma unroll
    for (int g = 0; g < 2; ++g)
#pragma unroll
        for (int p = 0; p < 4; ++p) g22[g][p] = mkv(0.f, 0.f);
#pragma unroll
    for (int j = 0; j < 16; ++j) {
        const float hA = (j & 1) ? h[0][j >> 1].y : h[0][j >> 1].x;
        const float hB = (j & 1) ? h[1][j >> 1].y : h[1][j >> 1].x;
        const v2f fa = mkv(hA, hA), fb = mkv(hB, hB);
#pragma unroll
        for (int p = 0; p < 4; ++p) {
            const v2f wp = *(const v2f*)(w2 + j * 8 + 2 * p);
            g22[0][p] = vfma(fa, wp, g22[0][p]);
            g22[1][p] = vfma(fb, wp, g22[1][p]);
        }
    }
    wavefence();   // g1 half-1 reads done -> overwrite g-rows with g2
#pragma unroll
    for (int g = 0; g < 2; ++g) {
        float4* gp = (float4*)(SBg[g] + v * 8);
        gp[0] = make_float4(g22[g][0].x, g22[g][0].y, g22[g][1].x, g22[g][1].y);
        gp[1] = make_float4(g22[g][2].x, g22[g][2].y, g22[g][3].x, g22[g][3].y);
    }
    wavefence();

    // ---- layer 2: h2 = leaky(W @ g2 + b2) ----
    v2f m2[2][4];
#pragma unroll
    for (int g = 0; g < 2; ++g)
#pragma unroll
        for (int p = 0; p < 4; ++p) m2[g][p] = mkv(0.f, 0.f);
#pragma unroll
    for (int g = 0; g < 2; ++g)
#pragma unroll
        for (int w = 0; w < 8; ++w) {
            const float wv = (w & 1) ? W2[g][w >> 1].y : W2[g][w >> 1].x;
            const v2f f2 = mkv(wv, wv);
            const float4* gp = (const float4*)(SBg[g] + w * 8);
            const float4 q0 = gp[0], q1 = gp[1];
            m2[g][0] = vfma(f2, mkv(q0.x, q0.y), m2[g][0]);
            m2[g][1] = vfma(f2, mkv(q0.z, q0.w), m2[g][1]);
            m2[g][2] = vfma(f2, mkv(q1.x, q1.y), m2[g][2]);
            m2[g][3] = vfma(f2, mkv(q1.z, q1.w), m2[g][3]);
        }
    v2f h2[2][4];
    {
        const v2f k01 = mkv(0.01f, 0.01f);
#pragma unroll
        for (int g = 0; g < 2; ++g)
#pragma unroll
            for (int p = 0; p < 4; ++p) {
                const v2f t = m2[g][p] + *(const v2f*)(b2 + 2 * p);
                h2[g][p] = __builtin_elementwise_max(t, t * k01);
            }
    }

    // ---- gate logits: Y[o] = dot(h2, wg[o,:]) (wg pairs loaded once) ----
    float Ys[2][8];
#pragma unroll
    for (int o = 0; o < 8; ++o) {
        v2f aA = mkv(0.f, 0.f), aB = mkv(0.f, 0.f);
#pragma unroll
        for (int p = 0; p < 4; ++p) {
            const v2f wp = *(const v2f*)(wg + o * 8 + 2 * p);
            aA = vfma(h2[0][p], wp, aA);
            aB = vfma(h2[1][p], wp, aB);
        }
        Ys[0][o] = aA.x + aA.y;
        Ys[1][o] = aB.x + aB.y;
    }
    wavefence();   // g2 reads done -> overwrite with pool layout
#pragma unroll
    for (int g = 0; g < 2; ++g) {
        // interleaved (Y, h2) pairs: float4 j = (Y[2j], h2[2j], Y[2j+1], h2[2j+1])
        float4* pp = (float4*)(SBg[g] + v * 16);
        pp[0] = make_float4(Ys[g][0], h2[g][0].x, Ys[g][1], h2[g][0].y);
        pp[1] = make_float4(Ys[g][2], h2[g][1].x, Ys[g][3], h2[g][1].y);
        pp[2] = make_float4(Ys[g][4], h2[g][2].x, Ys[g][5], h2[g][2].y);
        pp[3] = make_float4(Ys[g][6], h2[g][3].x, Ys[g][7], h2[g][3].y);
    }
    wavefence();

    // ---- attention pooling (gate-row o = v) + classifier, per batch ----
    const int o = v;
#pragma unroll
    for (int g = 0; g < 2; ++g) {
        float yc[8], hc[8], ty[8];
#pragma unroll
        for (int vp = 0; vp < 8; ++vp) {
            const float2 q = *(const float2*)(SBg[g] + vp * 16 + o * 2);
            yc[vp] = q.x;
            hc[vp] = q.y;
            ty[vp] = SBg[g][128 + vp];
        }
        float xp = 0.f;
#pragma unroll
        for (int t = 0; t < 2; ++t) {
            const float tv = (float)t;
            float l[8];
            float lmx = -1e30f;
#pragma unroll
            for (int vp = 0; vp < 8; ++vp) {
                l[vp] = (ty[vp] == tv) ? yc[vp] : 0.f;
                lmx = fmaxf(lmx, l[vp]);
            }
            float esum = 0.f, num = 0.f;
#pragma unroll
            for (int vp = 0; vp < 8; ++vp) {
                const float e = __expf(l[vp] - lmx);
                esum += e;
                num  += (ty[vp] == tv) ? e * hc[vp] : 0.f;
            }
            xp += 0.5f * num / esum;
        }
        const float y0 = grp_sum8(xp * wfv0);
        const float y1 = grp_sum8(xp * wfv1);
        if (v == 0) {
            float2* op = (float2*)(out + b[g] * 2);
            *op = make_float2(y0 + bf[0], y1 + bf[1]);
        }
    }
}

extern "C" void kernel_launch(void* const* d_in, const int* in_sizes, int n_in,
                              void* d_out, int out_size, void* d_ws, size_t ws_size,
                              hipStream_t stream) {
    const float* x    = (const float*)d_in[0];
    const float* adj  = (const float*)d_in[1];
    const float* edge = (const float*)d_in[2];
    // d_in[3]=wa, d_in[4]=ba unused by the reference.
    const float* wb   = (const float*)d_in[5];
    const float* bb   = (const float*)d_in[6];
    const float* w1   = (const float*)d_in[7];
    const float* b1   = (const float*)d_in[8];
    const float* w2   = (const float*)d_in[9];
    const float* b2   = (const float*)d_in[10];
    const float* wg   = (const float*)d_in[11];
    // d_in[12]=bg drops out of the softmax (constant along the node axis).
    const float* wf   = (const float*)d_in[13];
    const float* bf   = (const float*)d_in[14];
    float* out = (float*)d_out;

    const int Btot    = in_sizes[0] / 264;            // B = 131072
    const int nGroups = (Btot + SLOTS - 1) / SLOTS;   // 2048

    gcn_fused<<<nGroups, NTHREADS, 0, stream>>>(x, adj, edge, wb, bb, w1, b1,
                                                w2, b2, wg, wf, bf, out, nGroups);
}